// Round 8
// baseline (437.578 us; speedup 1.0000x reference)
//
#include <hip/hip_runtime.h>
#include <cstdint>

// Problem constants
#define B_  4
#define H_  16
#define S_  2048
#define DH_ 64
#define E_  1024
#define M_  (B_ * S_)   // 8192 rows for all projection GEMMs

typedef __attribute__((ext_vector_type(8))) __bf16 bf16x8;
typedef __attribute__((ext_vector_type(4))) __bf16 bf16x4;
typedef __attribute__((ext_vector_type(4))) float  f32x4;

// fp32 -> bf16 (round-to-nearest-even), bit-level
__device__ __forceinline__ uint16_t f2bf(float f) {
    union { float f; uint32_t u; } v; v.f = f;
    uint32_t u = v.u;
    uint32_t r = (u + 0x7fffu + ((u >> 16) & 1u)) >> 16;
    return (uint16_t)r;
}
__device__ __forceinline__ uint32_t pack2(float a, float b) {
    return (uint32_t)f2bf(a) | ((uint32_t)f2bf(b) << 16);
}

// hardware packed fp32->bf16 (RNE), 2 values -> 1 dword.  lo in [15:0].
__device__ __forceinline__ uint32_t cvt_pk_bf16(float lo, float hi) {
    uint32_t r;
    asm("v_cvt_pk_bf16_f32 %0, %1, %2" : "=v"(r) : "v"(lo), "v"(hi));
    return r;
}

// 2^x directly on the trans pipe (v_exp_f32 computes 2^S0)
__device__ __forceinline__ float exp2_fast(float x) {
#if __has_builtin(__builtin_amdgcn_exp2f)
    return __builtin_amdgcn_exp2f(x);
#else
    float r; asm("v_exp_f32 %0, %1" : "=v"(r) : "v"(x)); return r;
#endif
}

// async global->LDS, 16B per lane. LDS dest is wave-uniform base; HW adds lane*16.
__device__ __forceinline__ void glds16(const void* g, void* lds_base) {
    __builtin_amdgcn_global_load_lds(
        (const __attribute__((address_space(1))) uint32_t*)g,
        (__attribute__((address_space(3))) uint32_t*)lds_base, 16, 0, 0);
}

// ---------------------------------------------------------------------------
// Kernel 1 (fused prep): cast Wq/Wk/Wv/Wo and query/key/value fp32 -> bf16.
// ---------------------------------------------------------------------------
__global__ void prep_kernel(const float* __restrict__ q, const float* __restrict__ k,
                            const float* __restrict__ v,
                            const float* __restrict__ w0, const float* __restrict__ w1,
                            const float* __restrict__ w2, const float* __restrict__ w3,
                            uint16_t* __restrict__ wbf,
                            uint16_t* __restrict__ qa, uint16_t* __restrict__ ka,
                            uint16_t* __restrict__ va) {
    int bid = blockIdx.x;
    const float* src; uint16_t* dst; int base;
    if (bid < 2048) {
        int i = bid * 256 + threadIdx.x;
        base = i * 8;                         // [0, 4*2^20)
        int wsel = base >> 20;
        src = (wsel == 0) ? w0 : (wsel == 1) ? w1 : (wsel == 2) ? w2 : w3;
        dst = wbf + base;
        base &= 1048575;
    } else {
        int r = bid - 2048;                   // [0, 12288)
        int sel = r >> 12;                    // 4096 blocks per activation
        int i = (r & 4095) * 256 + threadIdx.x;
        base = i * 8;                         // [0, 2^23)
        src = (sel == 0) ? q : (sel == 1) ? k : v;
        dst = ((sel == 0) ? qa : (sel == 1) ? ka : va) + base;
    }
    float4 a = *(const float4*)(src + base);
    float4 b = *(const float4*)(src + base + 4);
    uint4 o;
    o.x = pack2(a.x, a.y); o.y = pack2(a.z, a.w);
    o.z = pack2(b.x, b.y); o.w = pack2(b.z, b.w);
    *(uint4*)dst = o;
}

// ---------------------------------------------------------------------------
// Mask int32 -> bitmask in the transposed layout for the 512-thread attn:
// word (b,row,c) covers cols [c*32,+32).  Decompose row = qt8*256 + w*32 +
// mt*16 + quad*4 + r  (w: 0..7 waves, mt: 0..1), c = it*4 + js.  Word index:
//   ((((((b*8+qt8)*8 + w)*4 + js)*16 + it)*4 + quad)*2 + mt)*4 + r
// bit=1 -> masked.
// ---------------------------------------------------------------------------
__global__ void mask_bits_kernel(const int* __restrict__ mask, uint32_t* __restrict__ bits) {
    int idx = blockIdx.x * 256 + threadIdx.x;      // element in [B*S*S)
    uint64_t bl = __ballot(mask[idx] != 0);        // 64 consecutive cols of one row
    if ((threadIdx.x & 63) == 0) {
        int col  = idx & 2047;                     // base col of this wave
        int row  = (idx >> 11) & 2047;
        int b    = idx >> 22;
        int qt8  = row >> 8;
        int rw   = row & 255;
        int w    = rw >> 5, sl = rw & 31;
        int mt   = sl >> 4, quad = (sl >> 2) & 3, r = sl & 3;
        int c0   = col >> 5;                       // even word index
#pragma unroll
        for (int half = 0; half < 2; ++half) {
            int c  = c0 + half;
            int it = c >> 2, js = c & 3;
            size_t i = ((((((size_t)(b * 8 + qt8) * 8 + w) * 4 + js) * 16 + it)
                         * 4 + quad) * 2 + mt) * 4 + r;
            bits[i] = (uint32_t)(half ? (bl >> 32) : bl);
        }
    }
}

// ---------------------------------------------------------------------------
// Kernel 2 (R8): C = A @ W^T + bias GEMM, 256x128 tile, 4 waves each owning
// a 64x128 output strip (acc 4x8).  Mechanism: 64 MFMAs (~320cy) per wave
// per barrier-pair instead of 32 -> staging/barrier overhead per FLOP
// halves; B-panel staged once per 256 A-rows.
//   mode 0: fp32 out [8192,1024]
//   mode 1: bf16 out scattered to [B,H,S,Dh]
//   mode 2: bf16 out scattered to [B,H,Dh,S] (V transposed)
// q is scaled by 0.125*log2(e) so attention can use exp2 directly.
// XCD remap (32 m-tiles x 8 n-tiles): m=(id&7)*4+((id>>3)&3), n=id>>5 ->
// each XCD owns 4 m-panels x all n: A 2MB + B 2MB = its own L2.
// Registers (R3 arithmetic): acc 128 AGPR + af 16 + bf 32 + addr/epi ~40
// = ~216 unified < 256 cap at launch_bounds(256,2): no spill.
// ---------------------------------------------------------------------------
__global__ __launch_bounds__(256, 2)
void gemm_bt_kernel(const uint16_t* __restrict__ A0, const uint16_t* __restrict__ A1,
                    const uint16_t* __restrict__ A2,
                    const uint16_t* __restrict__ Bw0,
                    const float* __restrict__ bias0, const float* __restrict__ bias1,
                    const float* __restrict__ bias2,
                    void* __restrict__ out0, void* __restrict__ out1,
                    void* __restrict__ out2,
                    int multi) {
    const int z = blockIdx.z;
    const uint16_t* A  = (z == 0) ? A0 : (z == 1) ? A1 : A2;
    const uint16_t* Bw = Bw0 + (size_t)z * 1048576;
    const float* bias  = (z == 0) ? bias0 : (z == 1) ? bias1 : bias2;
    void* out          = (z == 0) ? out0 : (z == 1) ? out1 : out2;
    const float scale  = (multi && z == 0) ? 0.18033688f : 1.0f;  // 0.125*log2e
    const int mode     = multi ? ((z == 2) ? 2 : 1) : 0;

    // XCD-aware remap: id in 0..255, xcd = id&7 owns m-tiles [4*xcd,+4) x all n
    const int id = blockIdx.x + 8 * blockIdx.y;
    const int m0 = ((id & 7) * 4 + ((id >> 3) & 3)) * 256;
    const int n0 = (id >> 5) * 128;

    __shared__ __align__(16) uint16_t As[256 * 64];   // 32 KB
    __shared__ __align__(16) uint16_t Bs[128 * 64];   // 16 KB

    const int t    = threadIdx.x;
    const int w    = t >> 6;                // wave = m-strip 0..3
    const int lane = t & 63;
    const int ln   = lane & 15;
    const int quad = lane >> 4;

    f32x4 acc[4][8];
    const f32x4 z4 = {0.f, 0.f, 0.f, 0.f};
#pragma unroll
    for (int i = 0; i < 4; ++i)
#pragma unroll
        for (int j = 0; j < 8; ++j) acc[i][j] = z4;

    const char* Ag = (const char*)(A  + (size_t)m0 * E_);
    const char* Bg = (const char*)(Bw + (size_t)n0 * E_);
    const int rsub = lane >> 3;                         // 0..7
    const int colb = ((lane & 7) ^ rsub) * 16;          // swizzled source chunk

    for (int kk = 0; kk < E_; kk += 64) {
        // A: 256 rows x 128B; row r = c*32 + w*8 + rsub -> LDS r*128 linear
#pragma unroll
        for (int c = 0; c < 8; ++c)
            glds16(Ag + (size_t)(c * 32 + w * 8 + rsub) * 2048 + kk * 2 + colb,
                   (char*)As + c * 4096 + w * 1024);
        // B: 128 rows
#pragma unroll
        for (int c = 0; c < 4; ++c)
            glds16(Bg + (size_t)(c * 32 + w * 8 + rsub) * 2048 + kk * 2 + colb,
                   (char*)Bs + c * 4096 + w * 1024);
        __syncthreads();

#pragma unroll
        for (int ks = 0; ks < 2; ++ks) {
            bf16x8 af[4], bf[8];
#pragma unroll
            for (int mt = 0; mt < 4; ++mt)
                af[mt] = *(const bf16x8*)&As[(w * 64 + mt * 16 + ln) * 64 +
                                             (((ks * 4 + quad) ^ (ln & 7)) * 8)];
#pragma unroll
            for (int nt = 0; nt < 8; ++nt)
                bf[nt] = *(const bf16x8*)&Bs[(nt * 16 + ln) * 64 +
                                             (((ks * 4 + quad) ^ (ln & 7)) * 8)];
#pragma unroll
            for (int mt = 0; mt < 4; ++mt)
#pragma unroll
                for (int nt = 0; nt < 8; ++nt)
                    acc[mt][nt] = __builtin_amdgcn_mfma_f32_16x16x32_bf16(
                        af[mt], bf[nt], acc[mt][nt], 0, 0, 0);
        }
        __syncthreads();
    }

    // epilogue; C/D layout: row = quad*4 + r, col = ln
#pragma unroll
    for (int mt = 0; mt < 4; ++mt) {
        const int rowb = m0 + w * 64 + mt * 16 + quad * 4;
#pragma unroll
        for (int nt = 0; nt < 8; ++nt) {
            const int col = n0 + nt * 16 + ln;
            const float bsum = bias[col];
            if (mode == 2) {
                int bb = rowb >> 11, s0 = rowb & 2047, hh = col >> 6, d = col & 63;
                float v0 = acc[mt][nt][0] + bsum, v1 = acc[mt][nt][1] + bsum;
                float v2 = acc[mt][nt][2] + bsum, v3 = acc[mt][nt][3] + bsum;
                uint2 o; o.x = pack2(v0, v1); o.y = pack2(v2, v3);
                *(uint2*)((uint16_t*)out + (((size_t)bb * H_ + hh) * DH_ + d) * S_ + s0) = o;
            } else {
#pragma unroll
                for (int r = 0; r < 4; ++r) {
                    float vv = (acc[mt][nt][r] + bsum) * scale;
                    int rr = rowb + r;
                    if (mode == 1) {
                        int bb = rr >> 11, s = rr & 2047, hh = col >> 6, d = col & 63;
                        ((uint16_t*)out)[(((size_t)bb * H_ + hh) * S_ + s) * DH_ + d] = f2bf(vv);
                    } else {
                        ((float*)out)[(size_t)rr * E_ + col] = vv;
                    }
                }
            }
        }
    }
}

// ---------------------------------------------------------------------------
// Kernel 3: flash attention, 256-row Q-blocks, 8 x 32-row waves (best: R7).
// 512-thread blocks, 8 waves, wave w owns q-rows [w*32,+32); K/V staged once
// per 128-j tile and shared by all waves; wave-private P buffer; no-max
// softmax (q pre-scaled log2e/8); even/odd j-interleave -> cvt_pk packed P;
// transposed bitmask; direct store with in-wave l reduction; s_setprio on
// MFMA clusters.
// ---------------------------------------------------------------------------
__global__ __launch_bounds__(512, 4)
void attn_kernel(const uint16_t* __restrict__ qb, const uint16_t* __restrict__ kb,
                 const uint16_t* __restrict__ vtb, const uint32_t* __restrict__ mbits,
                 uint16_t* __restrict__ attn_out) {
    const int wg   = blockIdx.x;                // 0..511
    const int xcd  = wg & 7;
    const int rest = wg >> 3;                   // 0..63
    const int qt8  = rest & 7;                  // 256-row q block
    const int bh   = ((rest >> 3) << 3) | xcd;  // 0..63
    const int b    = bh >> 4, h = bh & 15;

    __shared__ __align__(16) char smem[51200];
    // K: [0,16384) | V^T: [16384,32768) | P: [32768,51200)
    uint16_t* p_all = (uint16_t*)(smem + 32768);

    const int t    = threadIdx.x;
    const int w    = t >> 6;                    // 0..7
    const int lane = t & 63;
    const int ln   = lane & 15;
    const int quad = lane >> 4;
    const int ln2  = ln << 1;

    const char* qg  = (const char*)(qb  + ((size_t)bh * S_ + qt8 * 256) * DH_);
    const char* kg  = (const char*)(kb  + (size_t)bh * S_ * DH_);
    const char* vtg = (const char*)(vtb + (size_t)bh * DH_ * S_);

    // ---- Q A-frags direct from global: wave's own 32 rows
    bf16x8 aq[2][2];
#pragma unroll
    for (int mt = 0; mt < 2; ++mt)
#pragma unroll
        for (int ks = 0; ks < 2; ++ks)
            aq[mt][ks] = *(const bf16x8*)(qg + (size_t)(w * 32 + mt * 16 + ln) * 128 +
                                          ks * 64 + quad * 16);

    f32x4 acc_o[2][4];
    const f32x4 z4 = {0.f, 0.f, 0.f, 0.f};
#pragma unroll
    for (int mt = 0; mt < 2; ++mt)
#pragma unroll
        for (int nt = 0; nt < 4; ++nt) acc_o[mt][nt] = z4;
    float lr[2][4];
#pragma unroll
    for (int mt = 0; mt < 2; ++mt)
#pragma unroll
        for (int r = 0; r < 4; ++r) lr[mt][r] = 0.f;

    uint16_t* pw = p_all + w * 1152;            // 32 rows x 36 u16, wave-private
    // transposed mask base for this (b,qt8,wave)
    const uint32_t* mw = mbits + (size_t)(b * 8 + qt8) * 16384 + w * 2048 + quad * 8;

    const int rsub = lane >> 3;                 // 0..7
    const int kcol = ((lane & 7) ^ rsub) * 16;  // swizzled source chunk (K)

    // ---- staging: tile -> single buffer (4 glds/thread)
    auto stage = [&](int tile) {
        const char* kt = kg + (size_t)tile * 16384;
        char* kbase = smem + w * 2048;          // wave w: phys rows [w*16,+16)
#pragma unroll
        for (int c = 0; c < 2; ++c) {
            const int pr    = w * 16 + c * 8 + rsub;            // phys row 0..127
            const int strip = pr >> 5, p = pr & 31;
            const int jrow  = (p < 16) ? (2 * p) : (2 * p - 31); // even/odd perm
            glds16(kt + (size_t)(strip * 32 + jrow) * 128 + kcol, kbase + c * 1024);
        }
        char* vbase = smem + 16384 + w * 2048;  // wave w: d rows [w*8,+8)
#pragma unroll
        for (int c = 0; c < 2; ++c) {
            int row = w * 8 + c * 4 + (lane >> 4);
            int gch = (lane & 15) ^ (row & 15);
            glds16(vtg + (size_t)row * (S_ * 2) + tile * 256 + gch * 16,
                   vbase + c * 1024);
        }
    };

    const uint16_t* k_lds  = (const uint16_t*)smem;
    const uint16_t* vt_lds = (const uint16_t*)(smem + 16384);

    for (int it = 0; it < 16; ++it) {
        stage(it);
        __syncthreads();    // staging visible to all waves

        // ---- 4 substrips of 32 j each
#pragma unroll
        for (int js = 0; js < 4; ++js) {
            // mask words: 2 x dwordx4 (r innermost), broadcast within quad
            uint4 mk4[2];
#pragma unroll
            for (int mt = 0; mt < 2; ++mt)
                mk4[mt] = *(const uint4*)(mw + js * 512 + it * 32 + mt * 4);
            // V^T B-frags for this substrip
            bf16x8 bv[4];
#pragma unroll
            for (int nt = 0; nt < 4; ++nt)
                bv[nt] = *(const bf16x8*)&vt_lds[(nt * 16 + ln) * 128 +
                                                 (((js * 4 + quad) ^ ln) * 8)];

            // scores: 32 q-rows x 32 j, 8 MFMAs
            f32x4 sc[2][2];
#pragma unroll
            for (int mt = 0; mt < 2; ++mt) { sc[mt][0] = z4; sc[mt][1] = z4; }
            __builtin_amdgcn_s_setprio(1);
#pragma unroll
            for (int ks = 0; ks < 2; ++ks) {
                bf16x8 bk0 = *(const bf16x8*)&k_lds[(js * 32 + ln) * 64 +
                                                    (((ks * 4 + quad) ^ (ln & 7)) * 8)];
                bf16x8 bk1 = *(const bf16x8*)&k_lds[(js * 32 + 16 + ln) * 64 +
                                                    (((ks * 4 + quad) ^ (ln & 7)) * 8)];
#pragma unroll
                for (int mt = 0; mt < 2; ++mt) {
                    sc[mt][0] = __builtin_amdgcn_mfma_f32_16x16x32_bf16(aq[mt][ks], bk0, sc[mt][0], 0, 0, 0);
                    sc[mt][1] = __builtin_amdgcn_mfma_f32_16x16x32_bf16(aq[mt][ks], bk1, sc[mt][1], 0, 0, 0);
                }
            }
            __builtin_amdgcn_s_setprio(0);

            // exp2 + mask + partial l + packed P write
#pragma unroll
            for (int mt = 0; mt < 2; ++mt) {
                const uint32_t* mkp = (const uint32_t*)&mk4[mt];
#pragma unroll
                for (int r = 0; r < 4; ++r) {
                    uint32_t sh = mkp[r] >> ln2;
                    float e0 = (sh & 1u) ? 0.f : exp2_fast(sc[mt][0][r]);
                    float e1 = (sh & 2u) ? 0.f : exp2_fast(sc[mt][1][r]);
                    lr[mt][r] += e0 + e1;
                    *(uint32_t*)&pw[(mt * 16 + quad * 4 + r) * 36 + ln2] = cvt_pk_bf16(e0, e1);
                }
            }
            // no barrier: pw is wave-private (lgkmcnt orders write->read)

            // PV: O[q][d] += P[q][j] * V^T[d][j], 8 MFMAs
            __builtin_amdgcn_s_setprio(1);
#pragma unroll
            for (int mt = 0; mt < 2; ++mt) {
                bf16x4 lo = *(const bf16x4*)&pw[(mt * 16 + ln) * 36 + quad * 8];
                bf16x4 hi = *(const bf16x4*)&pw[(mt * 16 + ln) * 36 + quad * 8 + 4];
                bf16x8 ap = __builtin_shufflevector(lo, hi, 0, 1, 2, 3, 4, 5, 6, 7);
#pragma unroll
                for (int nt = 0; nt < 4; ++nt)
                    acc_o[mt][nt] = __builtin_amdgcn_mfma_f32_16x16x32_bf16(ap, bv[nt], acc_o[mt][nt], 0, 0, 0);
            }
            __builtin_amdgcn_s_setprio(0);
        }
        __syncthreads();   // protect K/V before next tile's staging
    }

    // ---- reduce l within wave (sum over ln; each lane holds 2 adjacent cols)
    float invl[2][4];
#pragma unroll
    for (int mt = 0; mt < 2; ++mt)
#pragma unroll
        for (int r = 0; r < 4; ++r) {
            float v = lr[mt][r];
            v += __shfl_xor(v, 1);
            v += __shfl_xor(v, 2);
            v += __shfl_xor(v, 4);
            v += __shfl_xor(v, 8);
            invl[mt][r] = 1.0f / v;
        }

    // ---- direct store (wave owns its rows; no cross-wave reduction)
    const size_t orow0 = (size_t)b * S_ + qt8 * 256 + w * 32;
#pragma unroll
    for (int mt = 0; mt < 2; ++mt)
#pragma unroll
        for (int r = 0; r < 4; ++r) {
            const size_t row = orow0 + mt * 16 + quad * 4 + r;
#pragma unroll
            for (int nt = 0; nt < 4; ++nt)
                attn_out[row * E_ + h * 64 + nt * 16 + ln] =
                    f2bf(acc_o[mt][nt][r] * invl[mt][r]);
        }
}

// ---------------------------------------------------------------------------
// Launcher.  Workspace layout (MB):
//   [0,8)    Wq,Wk,Wv,Wo bf16
//   [8,24)   query bf16    [24,40) key bf16    [40,56) value bf16
//   [56,72)  q proj bf16 [B,H,S,Dh] (scaled log2e/8)
//   [72,88)  k proj bf16 [B,H,S,Dh]
//   [88,104) v proj bf16 [B,H,Dh,S] (transposed)
//   [104,120) attn out bf16 [B*S, E]
//   [120,122) mask bitmask (transposed layout, 2 MB)
// ---------------------------------------------------------------------------
extern "C" void kernel_launch(void* const* d_in, const int* in_sizes, int n_in,
                              void* d_out, int out_size, void* d_ws, size_t ws_size,
                              hipStream_t stream) {
    const float* query = (const float*)d_in[0];
    const float* key_  = (const float*)d_in[1];
    const float* value = (const float*)d_in[2];
    const int*   mask  = (const int*)d_in[3];
    const float* Wq = (const float*)d_in[4];
    const float* bq = (const float*)d_in[5];
    const float* Wk = (const float*)d_in[6];
    const float* bk = (const float*)d_in[7];
    const float* Wv = (const float*)d_in[8];
    const float* bv = (const float*)d_in[9];
    const float* Wo = (const float*)d_in[10];
    const float* bo = (const float*)d_in[11];

    char* ws = (char*)d_ws;
    uint16_t* wbf   = (uint16_t*)ws;
    uint16_t* qa    = (uint16_t*)(ws + (8u   << 20));
    uint16_t* ka    = (uint16_t*)(ws + (24u  << 20));
    uint16_t* va    = (uint16_t*)(ws + (40u  << 20));
    uint16_t* qproj = (uint16_t*)(ws + (56u  << 20));
    uint16_t* kproj = (uint16_t*)(ws + (72u  << 20));
    uint16_t* vtp   = (uint16_t*)(ws + (88u  << 20));
    uint16_t* atto  = (uint16_t*)(ws + (104u << 20));
    uint32_t* mbits = (uint32_t*)(ws + (120u << 20));

    prep_kernel<<<14336, 256, 0, stream>>>(query, key_, value, Wq, Wk, Wv, Wo,
                                           wbf, qa, ka, va);
    mask_bits_kernel<<<65536, 256, 0, stream>>>(mask, mbits);

    // q/k/v projections in one launch (z selects input/weight/output)
    gemm_bt_kernel<<<dim3(8, M_ / 256, 3), 256, 0, stream>>>(
        qa, ka, va, wbf, bq, bk, bv, qproj, kproj, vtp, 1);

    attn_kernel<<<dim3(512), 512, 0, stream>>>(
        qproj, kproj, vtp, mbits, atto);

    // final projection: A=atto, W=Wo (4th weight), fp32 out
    gemm_bt_kernel<<<dim3(8, M_ / 256, 1), 256, 0, stream>>>(
        atto, atto, atto, wbf + 3145728, bo, bo, bo, d_out, d_out, d_out, 0);
}

// Round 9
// 432.824 us; speedup vs baseline: 1.0110x; 1.0110x over previous
//
#include <hip/hip_runtime.h>
#include <cstdint>

// Problem constants
#define B_  4
#define H_  16
#define S_  2048
#define DH_ 64
#define E_  1024
#define M_  (B_ * S_)   // 8192 rows for all projection GEMMs

typedef __attribute__((ext_vector_type(8))) __bf16 bf16x8;
typedef __attribute__((ext_vector_type(4))) __bf16 bf16x4;
typedef __attribute__((ext_vector_type(4))) float  f32x4;

// fp32 -> bf16 (round-to-nearest-even), bit-level
__device__ __forceinline__ uint16_t f2bf(float f) {
    union { float f; uint32_t u; } v; v.f = f;
    uint32_t u = v.u;
    uint32_t r = (u + 0x7fffu + ((u >> 16) & 1u)) >> 16;
    return (uint16_t)r;
}
__device__ __forceinline__ uint32_t pack2(float a, float b) {
    return (uint32_t)f2bf(a) | ((uint32_t)f2bf(b) << 16);
}

// hardware packed fp32->bf16 (RNE), 2 values -> 1 dword.  lo in [15:0].
__device__ __forceinline__ uint32_t cvt_pk_bf16(float lo, float hi) {
    uint32_t r;
    asm("v_cvt_pk_bf16_f32 %0, %1, %2" : "=v"(r) : "v"(lo), "v"(hi));
    return r;
}

// 2^x directly on the trans pipe (v_exp_f32 computes 2^S0)
__device__ __forceinline__ float exp2_fast(float x) {
#if __has_builtin(__builtin_amdgcn_exp2f)
    return __builtin_amdgcn_exp2f(x);
#else
    float r; asm("v_exp_f32 %0, %1" : "=v"(r) : "v"(x)); return r;
#endif
}

// async global->LDS, 16B per lane. LDS dest is wave-uniform base; HW adds lane*16.
__device__ __forceinline__ void glds16(const void* g, void* lds_base) {
    __builtin_amdgcn_global_load_lds(
        (const __attribute__((address_space(1))) uint32_t*)g,
        (__attribute__((address_space(3))) uint32_t*)lds_base, 16, 0, 0);
}

// ---------------------------------------------------------------------------
// Kernel 1 (fused prep + mask):
// blocks [0,2048): weight cast fp32->bf16
// blocks [2048,14336): activation cast fp32->bf16
// blocks [14336,79872): mask int32 -> transposed bitmask for the 512-thread
//   attn.  Word (b,row,c) covers cols [c*32,+32); row = qt8*256 + w*32 +
//   mt*16 + quad*4 + r, c = it*4 + js.  Word index:
//   ((((((b*8+qt8)*8 + w)*4 + js)*16 + it)*4 + quad)*2 + mt)*4 + r.
//   bit=1 -> masked.
// One launch instead of two: fewer serialization boundaries, and both
// memory-bound phases fill the machine together.
// ---------------------------------------------------------------------------
__global__ void prep_kernel(const float* __restrict__ q, const float* __restrict__ k,
                            const float* __restrict__ v,
                            const float* __restrict__ w0, const float* __restrict__ w1,
                            const float* __restrict__ w2, const float* __restrict__ w3,
                            uint16_t* __restrict__ wbf,
                            uint16_t* __restrict__ qa, uint16_t* __restrict__ ka,
                            uint16_t* __restrict__ va,
                            const int* __restrict__ mask, uint32_t* __restrict__ bits) {
    int bid = blockIdx.x;
    if (bid >= 14336) {
        // ---- mask path
        int idx = (bid - 14336) * 256 + threadIdx.x;   // element in [B*S*S)
        uint64_t bl = __ballot(mask[idx] != 0);        // 64 consecutive cols of one row
        if ((threadIdx.x & 63) == 0) {
            int col  = idx & 2047;
            int row  = (idx >> 11) & 2047;
            int b    = idx >> 22;
            int qt8  = row >> 8;
            int rw   = row & 255;
            int w    = rw >> 5, sl = rw & 31;
            int mt   = sl >> 4, quad = (sl >> 2) & 3, r = sl & 3;
            int c0   = col >> 5;
#pragma unroll
            for (int half = 0; half < 2; ++half) {
                int c  = c0 + half;
                int it = c >> 2, js = c & 3;
                size_t i = ((((((size_t)(b * 8 + qt8) * 8 + w) * 4 + js) * 16 + it)
                             * 4 + quad) * 2 + mt) * 4 + r;
                bits[i] = (uint32_t)(half ? (bl >> 32) : bl);
            }
        }
        return;
    }
    const float* src; uint16_t* dst; int base;
    if (bid < 2048) {
        int i = bid * 256 + threadIdx.x;
        base = i * 8;                         // [0, 4*2^20)
        int wsel = base >> 20;
        src = (wsel == 0) ? w0 : (wsel == 1) ? w1 : (wsel == 2) ? w2 : w3;
        dst = wbf + base;
        base &= 1048575;
    } else {
        int r = bid - 2048;                   // [0, 12288)
        int sel = r >> 12;                    // 4096 blocks per activation
        int i = (r & 4095) * 256 + threadIdx.x;
        base = i * 8;                         // [0, 2^23)
        src = (sel == 0) ? q : (sel == 1) ? k : v;
        dst = ((sel == 0) ? qa : (sel == 1) ? ka : va) + base;
    }
    float4 a = *(const float4*)(src + base);
    float4 b = *(const float4*)(src + base + 4);
    uint4 o;
    o.x = pack2(a.x, a.y); o.y = pack2(a.z, a.w);
    o.z = pack2(b.x, b.y); o.w = pack2(b.z, b.w);
    *(uint4*)dst = o;
}

// ---------------------------------------------------------------------------
// Kernel 2 (R9 = R7 structure + occupancy 3): C = A @ W^T + bias, 128x128
// tile, 4 waves of 64x64, XOR-chunk swizzled glds16 staging.
//   mode 0: fp32 out [8192,1024]
//   mode 1: bf16 out scattered to [B,H,S,Dh]
//   mode 2: bf16 out scattered to [B,H,Dh,S] (V transposed)
// q is scaled by 0.125*log2(e) so attention can use exp2 directly.
// XCD remap: id=x+8y, m=(id&7)*8+((id>>3)&7), n=id>>6 -> each XCD owns 8
// m-panels x all n (own-L2 A reuse).
// Occupancy (R8 lesson: GEMM is latency-bound at 2 blk/CU with both pipes
// ~85% idle): __launch_bounds__(256,3) -> 3 waves/SIMD cap 170 regs.
// K-loop live set: acc 64 AGPR + af 32 + bf 32 + addr ~15 = ~145 <= 170 ->
// no main-loop spill; LDS 32KB x 3 = 96KB fits.
// ---------------------------------------------------------------------------
__global__ __launch_bounds__(256, 3)
void gemm_bt_kernel(const uint16_t* __restrict__ A0, const uint16_t* __restrict__ A1,
                    const uint16_t* __restrict__ A2,
                    const uint16_t* __restrict__ Bw0,
                    const float* __restrict__ bias0, const float* __restrict__ bias1,
                    const float* __restrict__ bias2,
                    void* __restrict__ out0, void* __restrict__ out1,
                    void* __restrict__ out2,
                    int multi) {
    const int z = blockIdx.z;
    const uint16_t* A  = (z == 0) ? A0 : (z == 1) ? A1 : A2;
    const uint16_t* Bw = Bw0 + (size_t)z * 1048576;
    const float* bias  = (z == 0) ? bias0 : (z == 1) ? bias1 : bias2;
    void* out          = (z == 0) ? out0 : (z == 1) ? out1 : out2;
    const float scale  = (multi && z == 0) ? 0.18033688f : 1.0f;  // 0.125*log2e
    const int mode     = multi ? ((z == 2) ? 2 : 1) : 0;

    // XCD-aware remap of (x,y) -> (m_tile, n_tile); bijective on 8x64 grid
    const int id  = blockIdx.x + 8 * blockIdx.y;   // linear%8 == x == XCD
    const int m0 = ((id & 7) * 8 + ((id >> 3) & 7)) * 128;
    const int n0 = (id >> 6) * 128;

    __shared__ __align__(16) uint16_t As[128 * 64];   // 16 KB
    __shared__ __align__(16) uint16_t Bs[128 * 64];   // 16 KB

    const int t    = threadIdx.x;
    const int w    = t >> 6;
    const int lane = t & 63;
    const int ln   = lane & 15;
    const int quad = lane >> 4;
    const int wr   = w >> 1;
    const int wc   = w & 1;

    f32x4 acc[4][4];
    const f32x4 z4 = {0.f, 0.f, 0.f, 0.f};
#pragma unroll
    for (int i = 0; i < 4; ++i)
#pragma unroll
        for (int j = 0; j < 4; ++j) acc[i][j] = z4;

    const char* Ag = (const char*)(A  + (size_t)m0 * E_);
    const char* Bg = (const char*)(Bw + (size_t)n0 * E_);
    const int rsub = lane >> 3;                         // 0..7
    const int colb = ((lane & 7) ^ rsub) * 16;          // swizzled source chunk

    for (int kk = 0; kk < E_; kk += 64) {
#pragma unroll
        for (int c = 0; c < 4; ++c) {
            glds16(Ag + (size_t)(c * 32 + w * 8 + rsub) * 2048 + kk * 2 + colb,
                   (char*)As + c * 4096 + w * 1024);
            glds16(Bg + (size_t)(c * 32 + w * 8 + rsub) * 2048 + kk * 2 + colb,
                   (char*)Bs + c * 4096 + w * 1024);
        }
        __syncthreads();

#pragma unroll
        for (int ks = 0; ks < 2; ++ks) {
            bf16x8 af[4], bf[4];
#pragma unroll
            for (int mt = 0; mt < 4; ++mt)
                af[mt] = *(const bf16x8*)&As[(wr * 64 + mt * 16 + ln) * 64 +
                                             (((ks * 4 + quad) ^ (ln & 7)) * 8)];
#pragma unroll
            for (int nt = 0; nt < 4; ++nt)
                bf[nt] = *(const bf16x8*)&Bs[(wc * 64 + nt * 16 + ln) * 64 +
                                             (((ks * 4 + quad) ^ (ln & 7)) * 8)];
#pragma unroll
            for (int mt = 0; mt < 4; ++mt)
#pragma unroll
                for (int nt = 0; nt < 4; ++nt)
                    acc[mt][nt] = __builtin_amdgcn_mfma_f32_16x16x32_bf16(
                        af[mt], bf[nt], acc[mt][nt], 0, 0, 0);
        }
        __syncthreads();
    }

    // epilogue; C/D layout: row = quad*4 + r, col = ln
#pragma unroll
    for (int mt = 0; mt < 4; ++mt) {
        const int rowb = m0 + wr * 64 + mt * 16 + quad * 4;
#pragma unroll
        for (int nt = 0; nt < 4; ++nt) {
            const int col = n0 + wc * 64 + nt * 16 + ln;
            const float bsum = bias[col];
            if (mode == 2) {
                int bb = rowb >> 11, s0 = rowb & 2047, hh = col >> 6, d = col & 63;
                float v0 = acc[mt][nt][0] + bsum, v1 = acc[mt][nt][1] + bsum;
                float v2 = acc[mt][nt][2] + bsum, v3 = acc[mt][nt][3] + bsum;
                uint2 o; o.x = pack2(v0, v1); o.y = pack2(v2, v3);
                *(uint2*)((uint16_t*)out + (((size_t)bb * H_ + hh) * DH_ + d) * S_ + s0) = o;
            } else {
#pragma unroll
                for (int r = 0; r < 4; ++r) {
                    float vv = (acc[mt][nt][r] + bsum) * scale;
                    int rr = rowb + r;
                    if (mode == 1) {
                        int bb = rr >> 11, s = rr & 2047, hh = col >> 6, d = col & 63;
                        ((uint16_t*)out)[(((size_t)bb * H_ + hh) * S_ + s) * DH_ + d] = f2bf(vv);
                    } else {
                        ((float*)out)[(size_t)rr * E_ + col] = vv;
                    }
                }
            }
        }
    }
}

// ---------------------------------------------------------------------------
// Kernel 3: flash attention, 256-row Q-blocks, 8 x 32-row waves (best: R7).
// 512-thread blocks, 8 waves, wave w owns q-rows [w*32,+32); K/V staged once
// per 128-j tile and shared by all waves; wave-private P buffer; no-max
// softmax (q pre-scaled log2e/8); even/odd j-interleave -> cvt_pk packed P;
// transposed bitmask; direct store with in-wave l reduction; s_setprio on
// MFMA clusters.
// ---------------------------------------------------------------------------
__global__ __launch_bounds__(512, 4)
void attn_kernel(const uint16_t* __restrict__ qb, const uint16_t* __restrict__ kb,
                 const uint16_t* __restrict__ vtb, const uint32_t* __restrict__ mbits,
                 uint16_t* __restrict__ attn_out) {
    const int wg   = blockIdx.x;                // 0..511
    const int xcd  = wg & 7;
    const int rest = wg >> 3;                   // 0..63
    const int qt8  = rest & 7;                  // 256-row q block
    const int bh   = ((rest >> 3) << 3) | xcd;  // 0..63
    const int b    = bh >> 4, h = bh & 15;

    __shared__ __align__(16) char smem[51200];
    // K: [0,16384) | V^T: [16384,32768) | P: [32768,51200)
    uint16_t* p_all = (uint16_t*)(smem + 32768);

    const int t    = threadIdx.x;
    const int w    = t >> 6;                    // 0..7
    const int lane = t & 63;
    const int ln   = lane & 15;
    const int quad = lane >> 4;
    const int ln2  = ln << 1;

    const char* qg  = (const char*)(qb  + ((size_t)bh * S_ + qt8 * 256) * DH_);
    const char* kg  = (const char*)(kb  + (size_t)bh * S_ * DH_);
    const char* vtg = (const char*)(vtb + (size_t)bh * DH_ * S_);

    // ---- Q A-frags direct from global: wave's own 32 rows
    bf16x8 aq[2][2];
#pragma unroll
    for (int mt = 0; mt < 2; ++mt)
#pragma unroll
        for (int ks = 0; ks < 2; ++ks)
            aq[mt][ks] = *(const bf16x8*)(qg + (size_t)(w * 32 + mt * 16 + ln) * 128 +
                                          ks * 64 + quad * 16);

    f32x4 acc_o[2][4];
    const f32x4 z4 = {0.f, 0.f, 0.f, 0.f};
#pragma unroll
    for (int mt = 0; mt < 2; ++mt)
#pragma unroll
        for (int nt = 0; nt < 4; ++nt) acc_o[mt][nt] = z4;
    float lr[2][4];
#pragma unroll
    for (int mt = 0; mt < 2; ++mt)
#pragma unroll
        for (int r = 0; r < 4; ++r) lr[mt][r] = 0.f;

    uint16_t* pw = p_all + w * 1152;            // 32 rows x 36 u16, wave-private
    // transposed mask base for this (b,qt8,wave)
    const uint32_t* mw = mbits + (size_t)(b * 8 + qt8) * 16384 + w * 2048 + quad * 8;

    const int rsub = lane >> 3;                 // 0..7
    const int kcol = ((lane & 7) ^ rsub) * 16;  // swizzled source chunk (K)

    // ---- staging: tile -> single buffer (4 glds/thread)
    auto stage = [&](int tile) {
        const char* kt = kg + (size_t)tile * 16384;
        char* kbase = smem + w * 2048;          // wave w: phys rows [w*16,+16)
#pragma unroll
        for (int c = 0; c < 2; ++c) {
            const int pr    = w * 16 + c * 8 + rsub;            // phys row 0..127
            const int strip = pr >> 5, p = pr & 31;
            const int jrow  = (p < 16) ? (2 * p) : (2 * p - 31); // even/odd perm
            glds16(kt + (size_t)(strip * 32 + jrow) * 128 + kcol, kbase + c * 1024);
        }
        char* vbase = smem + 16384 + w * 2048;  // wave w: d rows [w*8,+8)
#pragma unroll
        for (int c = 0; c < 2; ++c) {
            int row = w * 8 + c * 4 + (lane >> 4);
            int gch = (lane & 15) ^ (row & 15);
            glds16(vtg + (size_t)row * (S_ * 2) + tile * 256 + gch * 16,
                   vbase + c * 1024);
        }
    };

    const uint16_t* k_lds  = (const uint16_t*)smem;
    const uint16_t* vt_lds = (const uint16_t*)(smem + 16384);

    for (int it = 0; it < 16; ++it) {
        stage(it);
        __syncthreads();    // staging visible to all waves

        // ---- 4 substrips of 32 j each
#pragma unroll
        for (int js = 0; js < 4; ++js) {
            // mask words: 2 x dwordx4 (r innermost), broadcast within quad
            uint4 mk4[2];
#pragma unroll
            for (int mt = 0; mt < 2; ++mt)
                mk4[mt] = *(const uint4*)(mw + js * 512 + it * 32 + mt * 4);
            // V^T B-frags for this substrip
            bf16x8 bv[4];
#pragma unroll
            for (int nt = 0; nt < 4; ++nt)
                bv[nt] = *(const bf16x8*)&vt_lds[(nt * 16 + ln) * 128 +
                                                 (((js * 4 + quad) ^ ln) * 8)];

            // scores: 32 q-rows x 32 j, 8 MFMAs
            f32x4 sc[2][2];
#pragma unroll
            for (int mt = 0; mt < 2; ++mt) { sc[mt][0] = z4; sc[mt][1] = z4; }
            __builtin_amdgcn_s_setprio(1);
#pragma unroll
            for (int ks = 0; ks < 2; ++ks) {
                bf16x8 bk0 = *(const bf16x8*)&k_lds[(js * 32 + ln) * 64 +
                                                    (((ks * 4 + quad) ^ (ln & 7)) * 8)];
                bf16x8 bk1 = *(const bf16x8*)&k_lds[(js * 32 + 16 + ln) * 64 +
                                                    (((ks * 4 + quad) ^ (ln & 7)) * 8)];
#pragma unroll
                for (int mt = 0; mt < 2; ++mt) {
                    sc[mt][0] = __builtin_amdgcn_mfma_f32_16x16x32_bf16(aq[mt][ks], bk0, sc[mt][0], 0, 0, 0);
                    sc[mt][1] = __builtin_amdgcn_mfma_f32_16x16x32_bf16(aq[mt][ks], bk1, sc[mt][1], 0, 0, 0);
                }
            }
            __builtin_amdgcn_s_setprio(0);

            // exp2 + mask + partial l + packed P write
#pragma unroll
            for (int mt = 0; mt < 2; ++mt) {
                const uint32_t* mkp = (const uint32_t*)&mk4[mt];
#pragma unroll
                for (int r = 0; r < 4; ++r) {
                    uint32_t sh = mkp[r] >> ln2;
                    float e0 = (sh & 1u) ? 0.f : exp2_fast(sc[mt][0][r]);
                    float e1 = (sh & 2u) ? 0.f : exp2_fast(sc[mt][1][r]);
                    lr[mt][r] += e0 + e1;
                    *(uint32_t*)&pw[(mt * 16 + quad * 4 + r) * 36 + ln2] = cvt_pk_bf16(e0, e1);
                }
            }
            // no barrier: pw is wave-private (lgkmcnt orders write->read)

            // PV: O[q][d] += P[q][j] * V^T[d][j], 8 MFMAs
            __builtin_amdgcn_s_setprio(1);
#pragma unroll
            for (int mt = 0; mt < 2; ++mt) {
                bf16x4 lo = *(const bf16x4*)&pw[(mt * 16 + ln) * 36 + quad * 8];
                bf16x4 hi = *(const bf16x4*)&pw[(mt * 16 + ln) * 36 + quad * 8 + 4];
                bf16x8 ap = __builtin_shufflevector(lo, hi, 0, 1, 2, 3, 4, 5, 6, 7);
#pragma unroll
                for (int nt = 0; nt < 4; ++nt)
                    acc_o[mt][nt] = __builtin_amdgcn_mfma_f32_16x16x32_bf16(ap, bv[nt], acc_o[mt][nt], 0, 0, 0);
            }
            __builtin_amdgcn_s_setprio(0);
        }
        __syncthreads();   // protect K/V before next tile's staging
    }

    // ---- reduce l within wave (sum over ln; each lane holds 2 adjacent cols)
    float invl[2][4];
#pragma unroll
    for (int mt = 0; mt < 2; ++mt)
#pragma unroll
        for (int r = 0; r < 4; ++r) {
            float v = lr[mt][r];
            v += __shfl_xor(v, 1);
            v += __shfl_xor(v, 2);
            v += __shfl_xor(v, 4);
            v += __shfl_xor(v, 8);
            invl[mt][r] = 1.0f / v;
        }

    // ---- direct store (wave owns its rows; no cross-wave reduction)
    const size_t orow0 = (size_t)b * S_ + qt8 * 256 + w * 32;
#pragma unroll
    for (int mt = 0; mt < 2; ++mt)
#pragma unroll
        for (int r = 0; r < 4; ++r) {
            const size_t row = orow0 + mt * 16 + quad * 4 + r;
#pragma unroll
            for (int nt = 0; nt < 4; ++nt)
                attn_out[row * E_ + h * 64 + nt * 16 + ln] =
                    f2bf(acc_o[mt][nt][r] * invl[mt][r]);
        }
}

// ---------------------------------------------------------------------------
// Launcher.  Workspace layout (MB):
//   [0,8)    Wq,Wk,Wv,Wo bf16
//   [8,24)   query bf16    [24,40) key bf16    [40,56) value bf16
//   [56,72)  q proj bf16 [B,H,S,Dh] (scaled log2e/8)
//   [72,88)  k proj bf16 [B,H,S,Dh]
//   [88,104) v proj bf16 [B,H,Dh,S] (transposed)
//   [104,120) attn out bf16 [B*S, E]
//   [120,122) mask bitmask (transposed layout, 2 MB)
// ---------------------------------------------------------------------------
extern "C" void kernel_launch(void* const* d_in, const int* in_sizes, int n_in,
                              void* d_out, int out_size, void* d_ws, size_t ws_size,
                              hipStream_t stream) {
    const float* query = (const float*)d_in[0];
    const float* key_  = (const float*)d_in[1];
    const float* value = (const float*)d_in[2];
    const int*   mask  = (const int*)d_in[3];
    const float* Wq = (const float*)d_in[4];
    const float* bq = (const float*)d_in[5];
    const float* Wk = (const float*)d_in[6];
    const float* bk = (const float*)d_in[7];
    const float* Wv = (const float*)d_in[8];
    const float* bv = (const float*)d_in[9];
    const float* Wo = (const float*)d_in[10];
    const float* bo = (const float*)d_in[11];

    char* ws = (char*)d_ws;
    uint16_t* wbf   = (uint16_t*)ws;
    uint16_t* qa    = (uint16_t*)(ws + (8u   << 20));
    uint16_t* ka    = (uint16_t*)(ws + (24u  << 20));
    uint16_t* va    = (uint16_t*)(ws + (40u  << 20));
    uint16_t* qproj = (uint16_t*)(ws + (56u  << 20));
    uint16_t* kproj = (uint16_t*)(ws + (72u  << 20));
    uint16_t* vtp   = (uint16_t*)(ws + (88u  << 20));
    uint16_t* atto  = (uint16_t*)(ws + (104u << 20));
    uint32_t* mbits = (uint32_t*)(ws + (120u << 20));

    // fused cast + mask bitmask (one launch)
    prep_kernel<<<79872, 256, 0, stream>>>(query, key_, value, Wq, Wk, Wv, Wo,
                                           wbf, qa, ka, va, mask, mbits);

    // q/k/v projections in one launch (z selects input/weight/output)
    gemm_bt_kernel<<<dim3(E_ / 128, M_ / 128, 3), 256, 0, stream>>>(
        qa, ka, va, wbf, bq, bk, bv, qproj, kproj, vtp, 1);

    attn_kernel<<<dim3(512), 512, 0, stream>>>(
        qproj, kproj, vtp, mbits, atto);

    // final projection: A=atto, W=Wo (4th weight), fp32 out
    gemm_bt_kernel<<<dim3(E_ / 128, M_ / 128, 1), 256, 0, stream>>>(
        atto, atto, atto, wbf + 3145728, bo, bo, bo, d_out, d_out, d_out, 0);
}